// Round 1
// baseline (276.181 us; speedup 1.0000x reference)
//
#include <hip/hip_runtime.h>

#define VOCAB 32000
#define E 64
#define H 8
#define L 25
#define B 1000
#define T 512

#define CHUNK 8                      // timesteps per super-step
#define NCHUNK (T / CHUNK)           // 64
#define NSTEP (NCHUNK + L - 1)       // 88
#define BPB 2                        // batches per block
#define THREADS 448                  // 2*200 active, padded to 7 waves

// LDS layout: per (bloc, layer): 2 parities * CHUNK * 8 floats = 128 floats,
// padded to 132 floats (528B) so consecutive layers start 4 banks apart ->
// the 8 groups in a wave read disjoint bank quads (conflict-free broadcast).
#define LAYER_STRIDE 132
#define BLOC_STRIDE (L * LAYER_STRIDE)   // 3300 floats
#define LDS_FLOATS (BPB * BLOC_STRIDE)   // 6600 floats = 26.4 KB

// ---------------- phase 1: proj_table[v][j] = sum_k embedding[v][k] * W0[k][j]
__global__ __launch_bounds__(256) void proj_kernel(
    const float* __restrict__ emb, const float* __restrict__ w0,
    float* __restrict__ ptab)
{
    int gid = blockIdx.x * 256 + threadIdx.x;     // VOCAB*8 = 256000 threads
    if (gid >= VOCAB * H) return;
    int j = gid & 7;
    int r = gid >> 3;
    const float* e = emb + r * E;
    float a0 = 0.f, a1 = 0.f, a2 = 0.f, a3 = 0.f;
#pragma unroll
    for (int k = 0; k < E; k += 4) {
        a0 += e[k + 0] * w0[(k + 0) * H + j];
        a1 += e[k + 1] * w0[(k + 1) * H + j];
        a2 += e[k + 2] * w0[(k + 2) * H + j];
        a3 += e[k + 3] * w0[(k + 3) * H + j];
    }
    ptab[gid] = (a0 + a1) + (a2 + a3);
}

__device__ __forceinline__ float fast_tanh(float x) {
    float e2 = __expf(2.0f * x);
    return 1.0f - 2.0f / (e2 + 1.0f);     // exact +-1 saturation at inf
}

// ---------------- phase 2: layer-pipelined recurrence
__global__ __launch_bounds__(THREADS) void rnn_recur(
    const int*   __restrict__ x,      // [B,T]
    const float* __restrict__ h0,     // [L,B,H]
    const float* __restrict__ wrest,  // [L-1,H,H]
    const float* __restrict__ whh_g,  // [L,H,H]
    const float* __restrict__ bh,     // [L,H]
    const float* __restrict__ why,    // [H]
    const float* __restrict__ by,     // [1]
    const float* __restrict__ ptab,   // [VOCAB,H]
    float*       __restrict__ out)    // [B] logits ++ [L,B,H] h_last
{
    __shared__ __align__(16) float buf[LDS_FLOATS];

    const int tid = threadIdx.x;
    for (int k = tid; k < LDS_FLOATS; k += THREADS) buf[k] = 0.f;

    const int bloc = tid / 200;            // 0,1 (2 => padding threads)
    const int r    = tid - bloc * 200;
    const int i    = r >> 3;               // layer
    const int j    = r & 7;                // unit
    const bool active = (tid < BPB * 200);
    const int b = blockIdx.x * BPB + bloc;

    float wx[8], whh[8];
    float bias = 0.f, hj = 0.f;
    float* mybuf = &buf[(bloc < BPB ? bloc : 0) * BLOC_STRIDE + i * LAYER_STRIDE];
    const float* prevbuf = mybuf - LAYER_STRIDE;

    if (active) {
#pragma unroll
        for (int k = 0; k < 8; ++k) {
            whh[k] = whh_g[(i * 8 + k) * 8 + j];
            wx[k]  = (i > 0) ? wrest[((i - 1) * 8 + k) * 8 + j] : 0.f;
        }
        bias = bh[i * 8 + j];
        hj = h0[(i * B + b) * H + j];
    }
    __syncthreads();
    if (active) {
        // seed the parity-1 last-slot so chunk 0 reads h0
        mybuf[1 * (CHUNK * 8) + (CHUNK - 1) * 8 + j] = hj;
    }
    __syncthreads();

    const int xbase = b * T;

    for (int s = 0; s < NSTEP; ++s) {
        const int c = s - i;
        if (active && (unsigned)c < (unsigned)NCHUNK) {
            const int p  = c & 1;
            const int t0 = c * CHUNK;
            float* wptr = mybuf + p * (CHUNK * 8);
            const float* hp0 = mybuf + (p ^ 1) * (CHUNK * 8) + (CHUNK - 1) * 8;

            float4 ha = *(const float4*)hp0;
            float4 hb = *(const float4*)(hp0 + 4);

            if (i == 0) {
                int tok[CHUNK];
#pragma unroll
                for (int ct = 0; ct < CHUNK; ++ct) tok[ct] = x[xbase + t0 + ct];
                float pv[CHUNK];
#pragma unroll
                for (int ct = 0; ct < CHUNK; ++ct) pv[ct] = ptab[tok[ct] * H + j];
#pragma unroll
                for (int ct = 0; ct < CHUNK; ++ct) {
                    float a0 = pv[ct] + bias;
                    float a1 = ha.y * whh[1];
                    float a2 = ha.z * whh[2];
                    float a3 = ha.w * whh[3];
                    a0 += ha.x * whh[0];
                    a1 += hb.x * whh[4];
                    a2 += hb.y * whh[5];
                    a3 += hb.z * whh[6];
                    a0 += hb.w * whh[7];
                    float hn = fast_tanh((a0 + a1) + (a2 + a3));
                    wptr[ct * 8 + j] = hn;
                    hj = hn;
                    __builtin_amdgcn_wave_barrier();   // keep write before readback
                    ha = *(const float4*)(wptr + ct * 8);
                    hb = *(const float4*)(wptr + ct * 8 + 4);
                }
            } else {
                const float* iptr = prevbuf + p * (CHUNK * 8);
#pragma unroll
                for (int ct = 0; ct < CHUNK; ++ct) {
                    float4 ia = *(const float4*)(iptr + ct * 8);
                    float4 ib = *(const float4*)(iptr + ct * 8 + 4);
                    float a0 = bias      + ia.x * wx[0];
                    float a1 = ia.y * wx[1] + ia.z * wx[2];
                    float a2 = ia.w * wx[3] + ib.x * wx[4];
                    float a3 = ib.y * wx[5] + ib.z * wx[6];
                    a0 += ib.w * wx[7];
                    a1 += ha.x * whh[0];
                    a2 += ha.y * whh[1];
                    a3 += ha.z * whh[2];
                    a0 += ha.w * whh[3];
                    a1 += hb.x * whh[4];
                    a2 += hb.y * whh[5];
                    a3 += hb.z * whh[6];
                    a0 += hb.w * whh[7];
                    float hn = fast_tanh((a0 + a1) + (a2 + a3));
                    wptr[ct * 8 + j] = hn;
                    hj = hn;
                    __builtin_amdgcn_wave_barrier();
                    ha = *(const float4*)(wptr + ct * 8);
                    hb = *(const float4*)(wptr + ct * 8 + 4);
                }
            }

            if (c == NCHUNK - 1) {
                out[B + (i * B + b) * H + j] = hj;       // h_last
                if (i == L - 1) {
                    float part = hj * why[j];
                    part += __shfl_xor(part, 1, 8);
                    part += __shfl_xor(part, 2, 8);
                    part += __shfl_xor(part, 4, 8);
                    if (j == 0) out[b] = part + by[0];   // logits
                }
            }
        }
        __syncthreads();
    }
}

extern "C" void kernel_launch(void* const* d_in, const int* in_sizes, int n_in,
                              void* d_out, int out_size, void* d_ws, size_t ws_size,
                              hipStream_t stream) {
    const int*   x     = (const int*)d_in[0];
    const float* h0    = (const float*)d_in[1];
    const float* emb   = (const float*)d_in[2];
    const float* w0    = (const float*)d_in[3];
    const float* wrest = (const float*)d_in[4];
    const float* whh   = (const float*)d_in[5];
    const float* bh    = (const float*)d_in[6];
    const float* why   = (const float*)d_in[7];
    const float* by    = (const float*)d_in[8];
    float* out  = (float*)d_out;
    float* ptab = (float*)d_ws;                       // 1 MB scratch

    hipLaunchKernelGGL(proj_kernel, dim3((VOCAB * H + 255) / 256), dim3(256),
                       0, stream, emb, w0, ptab);
    hipLaunchKernelGGL(rnn_recur, dim3(B / BPB), dim3(THREADS),
                       0, stream, x, h0, wrest, whh, bh, why, by, ptab, out);
}

// Round 3
// 271.865 us; speedup vs baseline: 1.0159x; 1.0159x over previous
//
#include <hip/hip_runtime.h>

#define VOCAB 32000
#define E 64
#define H 8
#define L 25
#define B 1000
#define T 512

#define CHUNK 8                      // timesteps per super-step
#define NCHUNK (T / CHUNK)           // 64
#define NSTEP (NCHUNK + L - 1)       // 88
#define THREADS 256                  // 200 active (25 layer-groups x 8)

// Per-layer LDS: 2 parities * CHUNK*8 floats = 128, padded to 132 so the 8
// layer-groups of a wave land on disjoint bank quads (conflict-free b128).
#define LAYER_STRIDE 132
#define LDS_FLOATS (L * LAYER_STRIDE)    // 3300 floats = 13.2 KB

typedef float v2f __attribute__((ext_vector_type(2)));

// ---------------- phase 1: proj_table[v][j] = sum_k embedding[v][k] * W0[k][j]
__global__ __launch_bounds__(256) void proj_kernel(
    const float* __restrict__ emb, const float* __restrict__ w0,
    float* __restrict__ ptab)
{
    __shared__ float w0s[E * H];
    int tid = threadIdx.x;
    w0s[tid] = w0[tid];
    w0s[tid + 256] = w0[tid + 256];
    __syncthreads();

    int gid = blockIdx.x * 256 + tid;            // VOCAB*8 threads
    if (gid >= VOCAB * H) return;
    int j = gid & 7;
    int r = gid >> 3;
    const float4* e4 = (const float4*)(emb + r * E);
    float a0 = 0.f, a1 = 0.f, a2 = 0.f, a3 = 0.f;
#pragma unroll
    for (int k4 = 0; k4 < E / 4; ++k4) {
        float4 v = e4[k4];
        a0 += v.x * w0s[(4 * k4 + 0) * H + j];
        a1 += v.y * w0s[(4 * k4 + 1) * H + j];
        a2 += v.z * w0s[(4 * k4 + 2) * H + j];
        a3 += v.w * w0s[(4 * k4 + 3) * H + j];
    }
    ptab[gid] = (a0 + a1) + (a2 + a3);
}

__device__ __forceinline__ float fast_tanh(float x) {
    float e2 = __expf(2.0f * x);
    return 1.0f - 2.0f / (e2 + 1.0f);            // exact +-1 saturation
}

// 8-lane butterfly helpers: xor1/xor2 via quad-perm DPP (VALU), xor4 via
// ds_swizzle (LDS crossbar, conflict-free, no storage).
__device__ __forceinline__ float fxor1(float x) {
    return __int_as_float(__builtin_amdgcn_mov_dpp(__float_as_int(x), 0xB1, 0xF, 0xF, true));
}
__device__ __forceinline__ float fxor2(float x) {
    return __int_as_float(__builtin_amdgcn_mov_dpp(__float_as_int(x), 0x4E, 0xF, 0xF, true));
}
__device__ __forceinline__ float fxor4(float x) {
    return __int_as_float(__builtin_amdgcn_ds_swizzle(__float_as_int(x), 0x101F));
}

// ---------------- phase 2: layer-pipelined recurrence, h register-resident
__global__ __launch_bounds__(THREADS) void rnn_recur(
    const int*   __restrict__ x,      // [B,T]
    const float* __restrict__ h0,     // [L,B,H]
    const float* __restrict__ wrest,  // [L-1,H,H]
    const float* __restrict__ whh_g,  // [L,H,H]
    const float* __restrict__ bh,     // [L,H]
    const float* __restrict__ why,    // [H]
    const float* __restrict__ by,     // [1]
    const float* __restrict__ ptab,   // [VOCAB,H]
    float*       __restrict__ out)    // [B] logits ++ [L,B,H] h_last
{
    __shared__ __align__(16) float buf[LDS_FLOATS];

    const int tid = threadIdx.x;
    const int i = tid >> 3;               // layer
    const int j = tid & 7;                // unit
    const bool active = tid < L * H;      // 200
    const int b = blockIdx.x;

    // weights permuted so slot m multiplies h_{j^m}
    v2f wh01 = {0.f, 0.f}, wh23 = {0.f, 0.f}, wh45 = {0.f, 0.f}, wh67 = {0.f, 0.f};
    v2f wx01 = {0.f, 0.f}, wx23 = {0.f, 0.f}, wx45 = {0.f, 0.f}, wx67 = {0.f, 0.f};
    v2f h01  = {0.f, 0.f}, h23  = {0.f, 0.f}, h45  = {0.f, 0.f}, h67  = {0.f, 0.f};
    float bias = 0.f, byv = 0.f;
    float wy0 = 0.f, wy1 = 0.f, wy2 = 0.f, wy3 = 0.f,
          wy4 = 0.f, wy5 = 0.f, wy6 = 0.f, wy7 = 0.f;

    float* mybuf = &buf[i * LAYER_STRIDE];
    const float* prevbuf = mybuf - LAYER_STRIDE;

    if (active) {
        const float* whL = whh_g + i * 64;
        wh01 = (v2f){whL[(j ^ 0) * 8 + j], whL[(j ^ 1) * 8 + j]};
        wh23 = (v2f){whL[(j ^ 2) * 8 + j], whL[(j ^ 3) * 8 + j]};
        wh45 = (v2f){whL[(j ^ 4) * 8 + j], whL[(j ^ 5) * 8 + j]};
        wh67 = (v2f){whL[(j ^ 6) * 8 + j], whL[(j ^ 7) * 8 + j]};
        if (i > 0) {
            const float* wxL = wrest + (i - 1) * 64;
            wx01 = (v2f){wxL[0 * 8 + j], wxL[1 * 8 + j]};
            wx23 = (v2f){wxL[2 * 8 + j], wxL[3 * 8 + j]};
            wx45 = (v2f){wxL[4 * 8 + j], wxL[5 * 8 + j]};
            wx67 = (v2f){wxL[6 * 8 + j], wxL[7 * 8 + j]};
        }
        bias = bh[i * 8 + j];
        const float* h0p = h0 + (i * B + b) * H;
        h01 = (v2f){h0p[j ^ 0], h0p[j ^ 1]};
        h23 = (v2f){h0p[j ^ 2], h0p[j ^ 3]};
        h45 = (v2f){h0p[j ^ 4], h0p[j ^ 5]};
        h67 = (v2f){h0p[j ^ 6], h0p[j ^ 7]};
        if (i == L - 1) {
            wy0 = why[j ^ 0]; wy1 = why[j ^ 1]; wy2 = why[j ^ 2]; wy3 = why[j ^ 3];
            wy4 = why[j ^ 4]; wy5 = why[j ^ 5]; wy6 = why[j ^ 6]; wy7 = why[j ^ 7];
            byv = by[0];
        }
    }

    const int xbase = b * T;
    float pv[CHUNK];
    if (active && i == 0) {
#pragma unroll
        for (int ct = 0; ct < CHUNK; ++ct)
            pv[ct] = ptab[x[xbase + ct] * H + j];
    }

    for (int s = 0; s < NSTEP; ++s) {
        const int c = s - i;
        if (active && (unsigned)c < (unsigned)NCHUNK) {
            const int p = c & 1;
            float* wptr = mybuf + p * (CHUNK * 8);
            const float* iptr = prevbuf + p * (CHUNK * 8);

            int tokn[CHUNK];
            const bool pf = (i == 0) && (c + 1 < NCHUNK);
            if (pf) {
#pragma unroll
                for (int ct = 0; ct < CHUNK; ++ct)
                    tokn[ct] = x[xbase + (c + 1) * CHUNK + ct];
            }

#pragma unroll
            for (int ct = 0; ct < CHUNK; ++ct) {
                v2f acc, acc2;
                if (i == 0) {
                    acc  = (v2f){pv[ct] + bias, 0.f};
                    acc2 = (v2f){0.f, 0.f};
                } else {
                    float4 ia = *(const float4*)(iptr + ct * 8);
                    float4 ib = *(const float4*)(iptr + ct * 8 + 4);
                    acc   = (v2f){bias, 0.f};
                    acc  += (v2f){ia.x, ia.y} * wx01;
                    acc2  = (v2f){ia.z, ia.w} * wx23;
                    acc  += (v2f){ib.x, ib.y} * wx45;
                    acc2 += (v2f){ib.z, ib.w} * wx67;
                }
                acc  += h01 * wh01;
                acc2 += h23 * wh23;
                acc  += h45 * wh45;
                acc2 += h67 * wh67;
                v2f at = acc + acc2;
                float hn = fast_tanh(at.x + at.y);

                if (i < L - 1) wptr[ct * 8 + j] = hn;   // cross-layer handoff only

                // register all-gather of the group's 8 new h values
                float o1 = fxor1(hn);
                float p0 = fxor2(hn);
                float p1 = fxor2(o1);
                h01 = (v2f){hn, o1};
                h23 = (v2f){p0, p1};
                h45 = (v2f){fxor4(hn), fxor4(o1)};
                h67 = (v2f){fxor4(p0), fxor4(p1)};
            }

            if (pf) {
#pragma unroll
                for (int ct = 0; ct < CHUNK; ++ct)
                    pv[ct] = ptab[tokn[ct] * H + j];
            }

            if (c == NCHUNK - 1) {
                out[B + (i * B + b) * H + j] = h01.x;   // h_last
                if (i == L - 1) {
                    float lg = byv;
                    lg += h01.x * wy0 + h01.y * wy1;
                    lg += h23.x * wy2 + h23.y * wy3;
                    lg += h45.x * wy4 + h45.y * wy5;
                    lg += h67.x * wy6 + h67.y * wy7;
                    if (j == 0) out[b] = lg;            // logits
                }
            }
        }
        __syncthreads();
    }
}

extern "C" void kernel_launch(void* const* d_in, const int* in_sizes, int n_in,
                              void* d_out, int out_size, void* d_ws, size_t ws_size,
                              hipStream_t stream) {
    const int*   x     = (const int*)d_in[0];
    const float* h0    = (const float*)d_in[1];
    const float* emb   = (const float*)d_in[2];
    const float* w0    = (const float*)d_in[3];
    const float* wrest = (const float*)d_in[4];
    const float* whh   = (const float*)d_in[5];
    const float* bh    = (const float*)d_in[6];
    const float* why   = (const float*)d_in[7];
    const float* by    = (const float*)d_in[8];
    float* out  = (float*)d_out;
    float* ptab = (float*)d_ws;                       // 1 MB scratch

    hipLaunchKernelGGL(proj_kernel, dim3((VOCAB * H + 255) / 256), dim3(256),
                       0, stream, emb, w0, ptab);
    hipLaunchKernelGGL(rnn_recur, dim3(B), dim3(THREADS),
                       0, stream, x, h0, wrest, whh, bh, why, by, ptab, out);
}